// Round 6
// baseline (152.563 us; speedup 1.0000x reference)
//
#include <hip/hip_runtime.h>
#include <math.h>

#define N_TOK 8192
#define DIM   2048
#define NE    64
#define TOPK  4
#define THETA 2e-3f
#define TPB   32                      /* tokens per k_main block */
#define NBLK  (N_TOK / TPB)           /* 256 */
#define HSTR  16                      /* hist padding: 1 counter per 64B line */

typedef short bf16x8 __attribute__((ext_vector_type(8)));
typedef float f32x4  __attribute__((ext_vector_type(4)));

// ---- workspace layout (float offsets) ----
#define OFF_LOGITS 0                          /* N_TOK*NE = 524288 */
#define OFF_MAXV   (OFF_LOGITS + N_TOK * NE)
#define OFF_DENOM  (OFF_MAXV + N_TOK)
#define OFF_HIST   (OFF_DENOM + N_TOK)        /* int, NE*HSTR = 1024 */
#define OFF_WH     (OFF_HIST + NE * HSTR)     /* NE*DIM bf16, frag-packed */
#define OFF_WL     (OFF_WH + NE * DIM / 2)
#define OFF_WT     (OFF_WL + NE * DIM / 2)    /* NE*DIM fp32 transposed */
#define OFF_WTMP   (OFF_WT + NE * DIM)        /* N_TOK*TOPK */

// pack 2 fp32 -> 2 truncated bf16 (hi) and 2 truncated bf16 of residual (lo)
__device__ inline void cvt2(float a, float b, unsigned& hi, unsigned& lo) {
    const unsigned ua = __float_as_uint(a), ub = __float_as_uint(b);
    hi = __builtin_amdgcn_perm(ub, ua, 0x07060302u);   // [a_hi16, b_hi16]
    const float ra = a - __uint_as_float(ua & 0xFFFF0000u);
    const float rb = b - __uint_as_float(ub & 0xFFFF0000u);
    lo = __builtin_amdgcn_perm(__float_as_uint(rb), __float_as_uint(ra), 0x07060302u);
}

union FragU { unsigned u[4]; bf16x8 v; uint4 q; };

__device__ inline void make_frags(const float4& p, const float4& q,
                                  bf16x8& hi, bf16x8& lo) {
    FragU H, L;
    cvt2(p.x, p.y, H.u[0], L.u[0]);
    cvt2(p.z, p.w, H.u[1], L.u[1]);
    cvt2(q.x, q.y, H.u[2], L.u[2]);
    cvt2(q.z, q.w, H.u[3], L.u[3]);
    hi = H.v; lo = L.v;
}

// W -> frag-packed (wh2, wl2): element for (kc, nt, lane, j) is
// W[e = nt*16 + (lane&15)][k = kc*32 + (lane>>4)*8 + j], stored at
// elem offset (kc*4+nt)*512 + lane*8 + j  -> contiguous 1KB/wave reads,
// and window win's B slice is the contiguous 32KB at win*32768 bytes.
// Also wt fp32 transpose [k][e] for exact recompute, and hist zero.
__global__ __launch_bounds__(256)
void k_wc(const float* __restrict__ W, unsigned short* __restrict__ wh2,
          unsigned short* __restrict__ wl2, float* __restrict__ wt,
          int* __restrict__ hist) {
    const int t = blockIdx.x * 256 + threadIdx.x;     // 0..16383
    if (t < NE * HSTR) hist[t] = 0;
    const int l  = t & 63;
    const int grp = t >> 6;                           // = kc*4 + nt, 0..255
    const int nt = grp & 3;
    const int kc = grp >> 2;
    const int e  = nt * 16 + (l & 15);
    const int k0 = kc * 32 + (l >> 4) * 8;

    const float4 p = *reinterpret_cast<const float4*>(W + (size_t)e * DIM + k0);
    const float4 q = *reinterpret_cast<const float4*>(W + (size_t)e * DIM + k0 + 4);
    FragU H, L;
    cvt2(p.x, p.y, H.u[0], L.u[0]);
    cvt2(p.z, p.w, H.u[1], L.u[1]);
    cvt2(q.x, q.y, H.u[2], L.u[2]);
    cvt2(q.z, q.w, H.u[3], L.u[3]);
    const size_t off = (size_t)grp * 512 + l * 8;
    *reinterpret_cast<uint4*>(wh2 + off) = H.q;
    *reinterpret_cast<uint4*>(wl2 + off) = L.q;

    wt[(size_t)(k0 + 0) * NE + e] = p.x;
    wt[(size_t)(k0 + 1) * NE + e] = p.y;
    wt[(size_t)(k0 + 2) * NE + e] = p.z;
    wt[(size_t)(k0 + 3) * NE + e] = p.w;
    wt[(size_t)(k0 + 4) * NE + e] = q.x;
    wt[(size_t)(k0 + 5) * NE + e] = q.y;
    wt[(size_t)(k0 + 6) * NE + e] = q.z;
    wt[(size_t)(k0 + 7) * NE + e] = q.w;
}

// global_load_lds-staged GEMM. 8 waves = 2 token-groups x 4 expert-groups;
// wave owns a full 16x16 logit tile over all K (no cross-wave reduction).
// Per 256-k window: stage A (32KB, XOR-swizzled source, linear LDS dest) +
// Bh/Bl (64KB frag-packed, linear copy) via global_load_lds (zero VGPR cost,
// whole 96KB in flight) -> barrier -> 8 chunks x {4 ds_read, cvt, 3 MFMA}.
__global__ __launch_bounds__(512, 2)
void k_main(const float* __restrict__ x, const unsigned short* __restrict__ wh2,
            const unsigned short* __restrict__ wl2, const float* __restrict__ bias,
            const float* __restrict__ wt,
            float* __restrict__ logits, float* __restrict__ maxv,
            float* __restrict__ denomv, int* __restrict__ hist,
            float* __restrict__ out) {
    __shared__ __align__(16) char smem[98304];        // A 32K | Bh 32K | Bl 32K
    __shared__ float lbuf[TPB][68];                   // 8704 B
    __shared__ float part[8][68];                     // 2176 B
    __shared__ int   selS[TPB];
    __shared__ float wS[TPB];
    __shared__ short flagIdx[TPB];
    __shared__ int   flagCnt;

    const int tid = threadIdx.x;
    const int ww  = tid >> 6;            // wave 0..7
    const int l   = tid & 63;
    const int t0  = blockIdx.x * TPB;
    const int m   = l & 15;              // token-low (A row) / expert-low (B)
    const int g   = l >> 4;              // k-octet group
    const int tg  = ww >> 2;             // token group 0..1
    const int eg  = ww & 3;              // expert group 0..3

    if (tid == 0) flagCnt = 0;

    // stage window win: wave ww copies bytes [ww*12K, ww*12K+12K) of smem.
    // A region  [0,32K):  row r = d>>10, physical 16B-slot p=(d>>4)&63 holds
    //                     logical slot s = p ^ (r&7)  (bank spread on read).
    // Bh region [32K,64K): linear from wh2 + win*32K.
    // Bl region [64K,96K): linear from wl2 + win*32K.
    auto stage = [&](int win) {
        #pragma unroll
        for (int j = 0; j < 12; ++j) {
            const int dbase = ww * 12288 + j * 1024;   // wave-uniform
            const int d = dbase + l * 16;              // this lane's byte
            const char* src;
            if (dbase < 32768) {
                const int r = d >> 10;
                const int s = ((d >> 4) & 63) ^ (r & 7);
                src = (const char*)(x + (size_t)(t0 + r) * DIM + win * 256 + s * 4);
            } else if (dbase < 65536) {
                src = (const char*)wh2 + (size_t)win * 32768 + (d - 32768);
            } else {
                src = (const char*)wl2 + (size_t)win * 32768 + (d - 65536);
            }
            __builtin_amdgcn_global_load_lds(
                (const __attribute__((address_space(1))) void*)src,
                (__attribute__((address_space(3))) void*)(smem + dbase),
                16, 0, 0);
        }
    };

    stage(0);
    asm volatile("s_waitcnt vmcnt(0)" ::: "memory");
    __syncthreads();

    f32x4 accA, accB;
    #pragma unroll
    for (int r = 0; r < 4; ++r) { accA[r] = 0.0f; accB[r] = 0.0f; }

    const int   arow  = tg * 16 + m;
    const char* aBase = smem + arow * 1024;
    const int   axor  = arow & 7;
    const char* bhB   = smem + 32768 + eg * 1024 + l * 16;

    for (int win = 0; win < 8; ++win) {
        #pragma unroll
        for (int kc = 0; kc < 8; ++kc) {
            const int s0 = kc * 8 + g * 2;
            const float4 p = *reinterpret_cast<const float4*>(aBase + ((s0 ^ axor) << 4));
            const float4 q = *reinterpret_cast<const float4*>(aBase + (((s0 + 1) ^ axor) << 4));
            FragU bh_, bl_;
            bh_.q = *reinterpret_cast<const uint4*>(bhB + kc * 4096);
            bl_.q = *reinterpret_cast<const uint4*>(bhB + 32768 + kc * 4096);
            bf16x8 ah, al;
            make_frags(p, q, ah, al);
            accA = __builtin_amdgcn_mfma_f32_16x16x32_bf16(ah, bh_.v, accA, 0, 0, 0);
            accB = __builtin_amdgcn_mfma_f32_16x16x32_bf16(al, bh_.v, accB, 0, 0, 0);
            accB = __builtin_amdgcn_mfma_f32_16x16x32_bf16(ah, bl_.v, accB, 0, 0, 0);
        }
        if (win < 7) {
            __syncthreads();             // all waves done reading this window
            stage(win + 1);
            asm volatile("s_waitcnt vmcnt(0)" ::: "memory");
            __syncthreads();             // window staged
        }
    }

    // wave's 16x16 tile -> lbuf (C/D map: col = lane&15, row = g*4+r)
    {
        const float be = bias[eg * 16 + m];
        #pragma unroll
        for (int r = 0; r < 4; ++r)
            lbuf[tg * 16 + g * 4 + r][eg * 16 + m] = accA[r] + accB[r] + be;
    }
    __syncthreads();

    for (int e2 = tid; e2 < TPB * NE; e2 += 512) {
        const int t = e2 >> 6, e = e2 & 63;
        logits[(size_t)(t0 + t) * NE + e] = lbuf[t][e];
    }

    #pragma unroll
    for (int tt = 0; tt < 4; ++tt) {
        const int t = ww * 4 + tt;
        const float lv = lbuf[t][l];
        float v1 = lv; int i1 = l; float v2 = -INFINITY;
        #pragma unroll
        for (int off = 32; off; off >>= 1) {
            const float ov1 = __shfl_xor(v1, off);
            const int   oi1 = __shfl_xor(i1, off);
            const float ov2 = __shfl_xor(v2, off);
            if (ov1 > v1 || (ov1 == v1 && oi1 < i1)) {
                v2 = fmaxf(v1, ov2); v1 = ov1; i1 = oi1;
            } else {
                v2 = fmaxf(v2, ov1);
            }
        }
        float s = expf(lv - v1);
        #pragma unroll
        for (int off = 32; off; off >>= 1) s += __shfl_xor(s, off);
        if (l == 0) {
            const int row = t0 + t;
            maxv[row]   = v1;
            denomv[row] = s;
            selS[t]     = i1;
            wS[t]       = 1.0f / s;
            if (v1 - v2 < THETA) {
                const int ix = atomicAdd(&flagCnt, 1);
                flagIdx[ix] = (short)t;
            }
        }
    }
    __syncthreads();

    // ---- in-block exact fp32 recompute for flagged (near-tie) tokens ----
    const int nf = flagCnt;
    for (int fi = 0; fi < nf; ++fi) {
        const int tl  = flagIdx[fi];
        const int row = t0 + tl;
        // 8 waves split K: wave ww covers k in [ww*256, ww*256+256); lane = expert
        const float* xr = x + (size_t)row * DIM + ww * 256;
        const float* wb = wt + (size_t)(ww * 256) * NE + l;
        float a0 = 0.0f, a1 = 0.0f;
        #pragma unroll 4
        for (int k = 0; k < 256; k += 8) {
            const float4 x0 = *reinterpret_cast<const float4*>(xr + k);
            const float4 x1 = *reinterpret_cast<const float4*>(xr + k + 4);
            a0 = fmaf(x0.x, wb[(size_t)(k + 0) * NE], a0);
            a0 = fmaf(x0.y, wb[(size_t)(k + 1) * NE], a0);
            a0 = fmaf(x0.z, wb[(size_t)(k + 2) * NE], a0);
            a0 = fmaf(x0.w, wb[(size_t)(k + 3) * NE], a0);
            a1 = fmaf(x1.x, wb[(size_t)(k + 4) * NE], a1);
            a1 = fmaf(x1.y, wb[(size_t)(k + 5) * NE], a1);
            a1 = fmaf(x1.z, wb[(size_t)(k + 6) * NE], a1);
            a1 = fmaf(x1.w, wb[(size_t)(k + 7) * NE], a1);
        }
        part[ww][l] = a0 + a1;
        __syncthreads();
        if (ww == 0) {
            float lg = bias[l];
            #pragma unroll
            for (int s2 = 0; s2 < 8; ++s2) lg += part[s2][l];
            logits[(size_t)row * NE + l] = lg;
            float v = lg; int idx = l;
            #pragma unroll
            for (int off = 32; off; off >>= 1) {
                const float ov = __shfl_xor(v, off);
                const int   oi = __shfl_xor(idx, off);
                if (ov > v || (ov == v && oi < idx)) { v = ov; idx = oi; }
            }
            float p = expf(lg - v);
            #pragma unroll
            for (int off = 32; off; off >>= 1) p += __shfl_xor(p, off);
            if (l == 0) {
                maxv[row]   = v;
                denomv[row] = p;
                selS[tl]    = idx;
                wS[tl]      = 1.0f / p;
            }
        }
        __syncthreads();
    }

    // ---- selection histogram: wave 0, lane = expert; padded counters ----
    if (ww == 0) {
        int cnt = 0;
        #pragma unroll
        for (int t = 0; t < TPB; ++t) cnt += (selS[t] == l) ? 1 : 0;
        if (cnt) atomicAdd(&hist[l * HSTR], cnt);
    }

    // ---- fast-path out write (k_decide fixes up only on capacity overflow) --
    if (tid < TPB) {
        const int row = t0 + tid;
        const float se = (float)selS[tid];
        const float wv = wS[tid];
        const float wn = wv / (4.0f * wv + 1e-8f);
        *reinterpret_cast<float4*>(out + (size_t)row * 4) = make_float4(se, se, se, se);
        *reinterpret_cast<float4*>(out + (size_t)N_TOK * TOPK + (size_t)row * 4) =
            make_float4(wn, wn, wn, wn);
    }
}

// capacity check from hist; out already holds the fast path. Single block:
// if any expert over capacity, run the exact serial fallback.
__global__ __launch_bounds__(256)
void k_decide(const int* __restrict__ hist, const float* __restrict__ logits,
              const float* __restrict__ maxv, const float* __restrict__ denomv,
              const int* __restrict__ tc, float* __restrict__ out,
              float* __restrict__ wtmp) {
    __shared__ int flagS;
    const int tid = threadIdx.x;
    const int cap = tc[0] / TOPK;
    if (tid < NE) {
        const bool bad = (TOPK * hist[tid * HSTR] > cap);
        const unsigned long long mm = __ballot(bad);
        if (tid == 0) flagS = (mm == 0ull) ? 1 : 0;
    }
    __syncthreads();
    if (flagS) return;                 // fast path already written by k_main

    if (tid < 64) {
        const int e = tid;
        int rem = cap;
        for (int k = 0; k < TOPK; ++k) {
            for (int b = 0; b < N_TOK; ++b) {
                const float lg = logits[(size_t)b * NE + e];
                float v = (rem > 0) ? lg : -INFINITY;
                int idx = e;
                #pragma unroll
                for (int off = 32; off; off >>= 1) {
                    const float ov = __shfl_xor(v, off);
                    const int   oi = __shfl_xor(idx, off);
                    if (ov > v || (ov == v && oi < idx)) { v = ov; idx = oi; }
                }
                const bool ok = (v != -INFINITY);
                if (ok && e == idx) rem -= 1;
                const float lc = __shfl(lg, idx);
                if (e == 0) {
                    out[(size_t)b * TOPK + k]  = ok ? (float)idx : -1.0f;
                    wtmp[(size_t)b * TOPK + k] = ok ? expf(lc - maxv[b]) / denomv[b] : 0.0f;
                }
            }
        }
    }
    __syncthreads();
    for (int b = tid; b < N_TOK; b += 256) {
        const float w0 = wtmp[b * 4 + 0], w1_ = wtmp[b * 4 + 1];
        const float w2 = wtmp[b * 4 + 2], w3 = wtmp[b * 4 + 3];
        const float s = ((w0 + w1_) + w2) + w3 + 1e-8f;
        out[N_TOK * TOPK + b * 4 + 0] = w0 / s;
        out[N_TOK * TOPK + b * 4 + 1] = w1_ / s;
        out[N_TOK * TOPK + b * 4 + 2] = w2 / s;
        out[N_TOK * TOPK + b * 4 + 3] = w3 / s;
    }
}

extern "C" void kernel_launch(void* const* d_in, const int* in_sizes, int n_in,
                              void* d_out, int out_size, void* d_ws, size_t ws_size,
                              hipStream_t stream) {
    const float* x    = (const float*)d_in[0];
    const float* W    = (const float*)d_in[1];
    const float* bias = (const float*)d_in[2];
    const int*   tc   = (const int*)d_in[3];

    float* ws       = (float*)d_ws;
    float* logits   = ws + OFF_LOGITS;
    float* maxv     = ws + OFF_MAXV;
    float* denomv   = ws + OFF_DENOM;
    int*   hist     = (int*)(ws + OFF_HIST);
    unsigned short* wh2 = (unsigned short*)(ws + OFF_WH);
    unsigned short* wl2 = (unsigned short*)(ws + OFF_WL);
    float* wt       = ws + OFF_WT;
    float* wtmp     = ws + OFF_WTMP;
    float* out      = (float*)d_out;

    k_wc<<<NE * DIM / 8 / 256, 256, 0, stream>>>(W, wh2, wl2, wt, hist);
    k_main<<<NBLK, 512, 0, stream>>>(x, wh2, wl2, bias, wt, logits, maxv,
                                     denomv, hist, out);
    k_decide<<<1, 256, 0, stream>>>(hist, logits, maxv, denomv, tc, out, wtmp);
}

// Round 7
// 149.636 us; speedup vs baseline: 1.0196x; 1.0196x over previous
//
#include <hip/hip_runtime.h>
#include <math.h>

#define N_TOK 8192
#define DIM   2048
#define NE    64
#define TOPK  4
#define THETA 2e-3f
#define TPB   32                      /* tokens per k_main block */
#define NBLK  (N_TOK / TPB)           /* 256 */
#define HSTR  16                      /* hist padding: 1 counter per 64B line */

typedef short bf16x8 __attribute__((ext_vector_type(8)));
typedef float f32x4  __attribute__((ext_vector_type(4)));

// ---- workspace layout (float offsets) ----
#define OFF_LOGITS 0                          /* N_TOK*NE = 524288 */
#define OFF_MAXV   (OFF_LOGITS + N_TOK * NE)
#define OFF_DENOM  (OFF_MAXV + N_TOK)
#define OFF_HIST   (OFF_DENOM + N_TOK)        /* int, NE*HSTR = 1024 */
#define OFF_WH     (OFF_HIST + NE * HSTR)     /* NE*DIM bf16, frag-packed */
#define OFF_WL     (OFF_WH + NE * DIM / 2)
#define OFF_WT     (OFF_WL + NE * DIM / 2)    /* NE*DIM fp32 transposed */
#define OFF_WTMP   (OFF_WT + NE * DIM)        /* N_TOK*TOPK */

// pack 2 fp32 -> 2 truncated bf16 (hi) and 2 truncated bf16 of residual (lo)
__device__ inline void cvt2(float a, float b, unsigned& hi, unsigned& lo) {
    const unsigned ua = __float_as_uint(a), ub = __float_as_uint(b);
    hi = __builtin_amdgcn_perm(ub, ua, 0x07060302u);   // [a_hi16, b_hi16]
    const float ra = a - __uint_as_float(ua & 0xFFFF0000u);
    const float rb = b - __uint_as_float(ub & 0xFFFF0000u);
    lo = __builtin_amdgcn_perm(__float_as_uint(rb), __float_as_uint(ra), 0x07060302u);
}

union FragU { unsigned u[4]; bf16x8 v; uint4 q; };

__device__ inline void make_frags(const float4& p, const float4& q,
                                  bf16x8& hi, bf16x8& lo) {
    FragU H, L;
    cvt2(p.x, p.y, H.u[0], L.u[0]);
    cvt2(p.z, p.w, H.u[1], L.u[1]);
    cvt2(q.x, q.y, H.u[2], L.u[2]);
    cvt2(q.z, q.w, H.u[3], L.u[3]);
    hi = H.v; lo = L.v;
}

// W -> frag-packed (wh2, wl2): element for (kc, nt, lane, j) is
// W[e = nt*16 + (lane&15)][k = kc*32 + (lane>>4)*8 + j], stored at
// elem offset (kc*4+nt)*512 + lane*8 + j.  kc-major => the B slice for a
// 128-k window win (kc = 4win..4win+3) is the contiguous 16KB at win*16384B.
// Also wt fp32 transpose [k][e] for exact recompute, and hist zero.
__global__ __launch_bounds__(256)
void k_wc(const float* __restrict__ W, unsigned short* __restrict__ wh2,
          unsigned short* __restrict__ wl2, float* __restrict__ wt,
          int* __restrict__ hist) {
    const int t = blockIdx.x * 256 + threadIdx.x;     // 0..16383
    if (t < NE * HSTR) hist[t] = 0;
    const int l  = t & 63;
    const int grp = t >> 6;                           // = kc*4 + nt, 0..255
    const int nt = grp & 3;
    const int kc = grp >> 2;
    const int e  = nt * 16 + (l & 15);
    const int k0 = kc * 32 + (l >> 4) * 8;

    const float4 p = *reinterpret_cast<const float4*>(W + (size_t)e * DIM + k0);
    const float4 q = *reinterpret_cast<const float4*>(W + (size_t)e * DIM + k0 + 4);
    FragU H, L;
    cvt2(p.x, p.y, H.u[0], L.u[0]);
    cvt2(p.z, p.w, H.u[1], L.u[1]);
    cvt2(q.x, q.y, H.u[2], L.u[2]);
    cvt2(q.z, q.w, H.u[3], L.u[3]);
    const size_t off = (size_t)grp * 512 + l * 8;
    *reinterpret_cast<uint4*>(wh2 + off) = H.q;
    *reinterpret_cast<uint4*>(wl2 + off) = L.q;

    wt[(size_t)(k0 + 0) * NE + e] = p.x;
    wt[(size_t)(k0 + 1) * NE + e] = p.y;
    wt[(size_t)(k0 + 2) * NE + e] = p.z;
    wt[(size_t)(k0 + 3) * NE + e] = p.w;
    wt[(size_t)(k0 + 4) * NE + e] = q.x;
    wt[(size_t)(k0 + 5) * NE + e] = q.y;
    wt[(size_t)(k0 + 6) * NE + e] = q.z;
    wt[(size_t)(k0 + 7) * NE + e] = q.w;
}

// gload_lds double-buffered GEMM, 32 tokens/block, 256 blocks (1/CU).
// 16 windows of K=128. Window buffer (48KB): A 16KB (XOR-swizzled source,
// linear LDS dest) | Bh 16KB | Bl 16KB (frag-packed, linear).
// Loop: issue stage(win+1) into other buffer -> compute(win) -> vmcnt(0)
// -> barrier.  The drain waits on loads that had a full compute phase to
// land (m97 pattern).  Waves: 2 token-groups x 4 k-chunks; partials
// reduced via red[4][32][68] aliased onto buffer 0 after the K-loop.
__global__ __launch_bounds__(512, 2)
void k_main(const float* __restrict__ x, const unsigned short* __restrict__ wh2,
            const unsigned short* __restrict__ wl2, const float* __restrict__ bias,
            const float* __restrict__ wt,
            float* __restrict__ logits, float* __restrict__ maxv,
            float* __restrict__ denomv, int* __restrict__ hist,
            float* __restrict__ out) {
    __shared__ __align__(16) char smem[2][49152];     // 96 KB
    __shared__ float lbuf[TPB][68];                   // 8704 B
    __shared__ float part[8][68];                     // 2176 B
    __shared__ int   selS[TPB];
    __shared__ float wS[TPB];
    __shared__ short flagIdx[TPB];
    __shared__ int   flagCnt;

    const int tid = threadIdx.x;
    const int ww  = tid >> 6;            // wave 0..7
    const int l   = tid & 63;
    const int t0  = blockIdx.x * TPB;
    const int m   = l & 15;              // token-low (A) / expert-low (B)
    const int g   = l >> 4;              // k-octet group
    const int tg  = ww >> 2;             // token group 0..1
    const int kcl = ww & 3;              // k-chunk within window 0..3

    if (tid == 0) flagCnt = 0;

    // stage window win into smem[bufsel]: wave ww copies 6KB.
    // A  [0,16K):   row r (512B) holds logical slot s at physical p=s^(r&15)
    // Bh [16K,32K): linear from wh2 + win*16K
    // Bl [32K,48K): linear from wl2 + win*16K
    auto stage = [&](int win, int bufsel) {
        #pragma unroll
        for (int j = 0; j < 6; ++j) {
            const int dbase = ww * 6144 + j * 1024;    // wave-uniform
            const int d = dbase + l * 16;
            const char* src;
            if (dbase < 16384) {
                const int r = d >> 9;                  // token row 0..31
                const int p = (d >> 4) & 31;           // physical slot
                const int s = p ^ (r & 15);            // logical slot
                src = (const char*)(x + (size_t)(t0 + r) * DIM + win * 128 + s * 4);
            } else if (dbase < 32768) {
                src = (const char*)wh2 + (size_t)win * 16384 + (d - 16384);
            } else {
                src = (const char*)wl2 + (size_t)win * 16384 + (d - 32768);
            }
            __builtin_amdgcn_global_load_lds(
                (const __attribute__((address_space(1))) void*)src,
                (__attribute__((address_space(3))) void*)(&smem[bufsel][dbase]),
                16, 0, 0);
        }
    };

    stage(0, 0);
    asm volatile("s_waitcnt vmcnt(0)" ::: "memory");
    __syncthreads();

    f32x4 accA[4], accB[4];
    #pragma unroll
    for (int nt = 0; nt < 4; ++nt)
        #pragma unroll
        for (int r = 0; r < 4; ++r) { accA[nt][r] = 0.0f; accB[nt][r] = 0.0f; }

    const int arow = tg * 16 + m;
    const int ax   = arow & 15;
    const int s0   = kcl * 8 + g * 2;

    for (int win = 0; win < 16; ++win) {
        const int cur = win & 1;
        if (win < 15) stage(win + 1, cur ^ 1);

        const char* A  = smem[cur] + arow * 512;
        const char* Bh = smem[cur] + 16384 + kcl * 4096 + l * 16;
        const char* Bl = smem[cur] + 32768 + kcl * 4096 + l * 16;

        const float4 p = *reinterpret_cast<const float4*>(A + ((s0 ^ ax) << 4));
        const float4 q = *reinterpret_cast<const float4*>(A + (((s0 + 1) ^ ax) << 4));
        bf16x8 ah, al;
        make_frags(p, q, ah, al);

        #pragma unroll
        for (int nt = 0; nt < 4; ++nt) {
            FragU b; b.q = *reinterpret_cast<const uint4*>(Bh + nt * 1024);
            accA[nt] = __builtin_amdgcn_mfma_f32_16x16x32_bf16(ah, b.v, accA[nt], 0, 0, 0);
            accB[nt] = __builtin_amdgcn_mfma_f32_16x16x32_bf16(al, b.v, accB[nt], 0, 0, 0);
        }
        #pragma unroll
        for (int nt = 0; nt < 4; ++nt) {
            FragU b; b.q = *reinterpret_cast<const uint4*>(Bl + nt * 1024);
            accB[nt] = __builtin_amdgcn_mfma_f32_16x16x32_bf16(ah, b.v, accB[nt], 0, 0, 0);
        }

        asm volatile("s_waitcnt vmcnt(0)" ::: "memory");
        __syncthreads();
    }

    // partials -> red (aliases smem[0]; K-loop reads finished at barrier)
    float* red = reinterpret_cast<float*>(&smem[0][0]);   // [4][32][68]
    #pragma unroll
    for (int nt = 0; nt < 4; ++nt)
        #pragma unroll
        for (int r = 0; r < 4; ++r)
            red[(kcl * TPB + tg * 16 + g * 4 + r) * 68 + nt * 16 + m] =
                accA[nt][r] + accB[nt][r];
    __syncthreads();

    for (int e2 = tid; e2 < TPB * NE; e2 += 512) {
        const int t = e2 >> 6, e = e2 & 63;
        float s = red[(0 * TPB + t) * 68 + e] + red[(1 * TPB + t) * 68 + e]
                + red[(2 * TPB + t) * 68 + e] + red[(3 * TPB + t) * 68 + e];
        s += bias[e];
        logits[(size_t)(t0 + t) * NE + e] = s;
        lbuf[t][e] = s;
    }
    __syncthreads();

    #pragma unroll
    for (int tt = 0; tt < 4; ++tt) {
        const int t = ww * 4 + tt;
        const float lv = lbuf[t][l];
        float v1 = lv; int i1 = l; float v2 = -INFINITY;
        #pragma unroll
        for (int off = 32; off; off >>= 1) {
            const float ov1 = __shfl_xor(v1, off);
            const int   oi1 = __shfl_xor(i1, off);
            const float ov2 = __shfl_xor(v2, off);
            if (ov1 > v1 || (ov1 == v1 && oi1 < i1)) {
                v2 = fmaxf(v1, ov2); v1 = ov1; i1 = oi1;
            } else {
                v2 = fmaxf(v2, ov1);
            }
        }
        float s = expf(lv - v1);
        #pragma unroll
        for (int off = 32; off; off >>= 1) s += __shfl_xor(s, off);
        if (l == 0) {
            const int row = t0 + t;
            maxv[row]   = v1;
            denomv[row] = s;
            selS[t]     = i1;
            wS[t]       = 1.0f / s;
            if (v1 - v2 < THETA) {
                const int ix = atomicAdd(&flagCnt, 1);
                flagIdx[ix] = (short)t;
            }
        }
    }
    __syncthreads();

    // ---- in-block exact fp32 recompute for flagged (near-tie) tokens ----
    const int nf = flagCnt;
    for (int fi = 0; fi < nf; ++fi) {
        const int tl  = flagIdx[fi];
        const int row = t0 + tl;
        const float* xr = x + (size_t)row * DIM + ww * 256;
        const float* wb = wt + (size_t)(ww * 256) * NE + l;
        float a0 = 0.0f, a1 = 0.0f;
        #pragma unroll 4
        for (int k = 0; k < 256; k += 8) {
            const float4 x0 = *reinterpret_cast<const float4*>(xr + k);
            const float4 x1 = *reinterpret_cast<const float4*>(xr + k + 4);
            a0 = fmaf(x0.x, wb[(size_t)(k + 0) * NE], a0);
            a0 = fmaf(x0.y, wb[(size_t)(k + 1) * NE], a0);
            a0 = fmaf(x0.z, wb[(size_t)(k + 2) * NE], a0);
            a0 = fmaf(x0.w, wb[(size_t)(k + 3) * NE], a0);
            a1 = fmaf(x1.x, wb[(size_t)(k + 4) * NE], a1);
            a1 = fmaf(x1.y, wb[(size_t)(k + 5) * NE], a1);
            a1 = fmaf(x1.z, wb[(size_t)(k + 6) * NE], a1);
            a1 = fmaf(x1.w, wb[(size_t)(k + 7) * NE], a1);
        }
        part[ww][l] = a0 + a1;
        __syncthreads();
        if (ww == 0) {
            float lg = bias[l];
            #pragma unroll
            for (int s2 = 0; s2 < 8; ++s2) lg += part[s2][l];
            logits[(size_t)row * NE + l] = lg;
            float v = lg; int idx = l;
            #pragma unroll
            for (int off = 32; off; off >>= 1) {
                const float ov = __shfl_xor(v, off);
                const int   oi = __shfl_xor(idx, off);
                if (ov > v || (ov == v && oi < idx)) { v = ov; idx = oi; }
            }
            float p = expf(lg - v);
            #pragma unroll
            for (int off = 32; off; off >>= 1) p += __shfl_xor(p, off);
            if (l == 0) {
                maxv[row]   = v;
                denomv[row] = p;
                selS[tl]    = idx;
                wS[tl]      = 1.0f / p;
            }
        }
        __syncthreads();
    }

    // ---- selection histogram: wave 0, lane = expert; padded counters ----
    if (ww == 0) {
        int cnt = 0;
        #pragma unroll
        for (int t = 0; t < TPB; ++t) cnt += (selS[t] == l) ? 1 : 0;
        if (cnt) atomicAdd(&hist[l * HSTR], cnt);
    }

    // ---- fast-path out write (k_decide fixes up only on capacity overflow) --
    if (tid < TPB) {
        const int row = t0 + tid;
        const float se = (float)selS[tid];
        const float wv = wS[tid];
        const float wn = wv / (4.0f * wv + 1e-8f);
        *reinterpret_cast<float4*>(out + (size_t)row * 4) = make_float4(se, se, se, se);
        *reinterpret_cast<float4*>(out + (size_t)N_TOK * TOPK + (size_t)row * 4) =
            make_float4(wn, wn, wn, wn);
    }
}

// capacity check from hist; out already holds the fast path. Single block:
// if any expert over capacity, run the exact serial fallback.
__global__ __launch_bounds__(256)
void k_decide(const int* __restrict__ hist, const float* __restrict__ logits,
              const float* __restrict__ maxv, const float* __restrict__ denomv,
              const int* __restrict__ tc, float* __restrict__ out,
              float* __restrict__ wtmp) {
    __shared__ int flagS;
    const int tid = threadIdx.x;
    const int cap = tc[0] / TOPK;
    if (tid < NE) {
        const bool bad = (TOPK * hist[tid * HSTR] > cap);
        const unsigned long long mm = __ballot(bad);
        if (tid == 0) flagS = (mm == 0ull) ? 1 : 0;
    }
    __syncthreads();
    if (flagS) return;                 // fast path already written by k_main

    if (tid < 64) {
        const int e = tid;
        int rem = cap;
        for (int k = 0; k < TOPK; ++k) {
            for (int b = 0; b < N_TOK; ++b) {
                const float lg = logits[(size_t)b * NE + e];
                float v = (rem > 0) ? lg : -INFINITY;
                int idx = e;
                #pragma unroll
                for (int off = 32; off; off >>= 1) {
                    const float ov = __shfl_xor(v, off);
                    const int   oi = __shfl_xor(idx, off);
                    if (ov > v || (ov == v && oi < idx)) { v = ov; idx = oi; }
                }
                const bool ok = (v != -INFINITY);
                if (ok && e == idx) rem -= 1;
                const float lc = __shfl(lg, idx);
                if (e == 0) {
                    out[(size_t)b * TOPK + k]  = ok ? (float)idx : -1.0f;
                    wtmp[(size_t)b * TOPK + k] = ok ? expf(lc - maxv[b]) / denomv[b] : 0.0f;
                }
            }
        }
    }
    __syncthreads();
    for (int b = tid; b < N_TOK; b += 256) {
        const float w0 = wtmp[b * 4 + 0], w1_ = wtmp[b * 4 + 1];
        const float w2 = wtmp[b * 4 + 2], w3 = wtmp[b * 4 + 3];
        const float s = ((w0 + w1_) + w2) + w3 + 1e-8f;
        out[N_TOK * TOPK + b * 4 + 0] = w0 / s;
        out[N_TOK * TOPK + b * 4 + 1] = w1_ / s;
        out[N_TOK * TOPK + b * 4 + 2] = w2 / s;
        out[N_TOK * TOPK + b * 4 + 3] = w3 / s;
    }
}

extern "C" void kernel_launch(void* const* d_in, const int* in_sizes, int n_in,
                              void* d_out, int out_size, void* d_ws, size_t ws_size,
                              hipStream_t stream) {
    const float* x    = (const float*)d_in[0];
    const float* W    = (const float*)d_in[1];
    const float* bias = (const float*)d_in[2];
    const int*   tc   = (const int*)d_in[3];

    float* ws       = (float*)d_ws;
    float* logits   = ws + OFF_LOGITS;
    float* maxv     = ws + OFF_MAXV;
    float* denomv   = ws + OFF_DENOM;
    int*   hist     = (int*)(ws + OFF_HIST);
    unsigned short* wh2 = (unsigned short*)(ws + OFF_WH);
    unsigned short* wl2 = (unsigned short*)(ws + OFF_WL);
    float* wt       = ws + OFF_WT;
    float* wtmp     = ws + OFF_WTMP;
    float* out      = (float*)d_out;

    k_wc<<<NE * DIM / 8 / 256, 256, 0, stream>>>(W, wh2, wl2, wt, hist);
    k_main<<<NBLK, 512, 0, stream>>>(x, wh2, wl2, bias, wt, logits, maxv,
                                     denomv, hist, out);
    k_decide<<<1, 256, 0, stream>>>(hist, logits, maxv, denomv, tc, out, wtmp);
}